// Round 1
// baseline (140.664 us; speedup 1.0000x reference)
//
#include <hip/hip_runtime.h>
#include <math.h>

#define M_ROWS 4096
#define IN_DIM 64
#define NCLS 10
#define ROW_STRIDE 74   // 64 tau + 10 labels
#define TWO_PI_F 6.283185307179586f

// ---------------- phi (Bessel-I0-based) ----------------
__device__ __forceinline__ float phi_f_eval(float s) {
    // s in [0, 7.5]
    float t = s * (1.0f / 7.5f);
    float t2 = t * t;
    float p = 0.0045813f;
    p = fmaf(p, t2, 0.0360768f);
    p = fmaf(p, t2, 0.2659732f);
    p = fmaf(p, t2, 1.2067492f);
    p = fmaf(p, t2, 3.0899424f);
    p = fmaf(p, t2, 3.5156229f);
    p = fmaf(p, t2, 1.0f);
    return __expf(-0.5f * s) * p;
}

__device__ __forceinline__ float phi_g_eval(float s) {
    // s >= 7.5
    float r = __builtin_amdgcn_rcpf(s);
    float u = 7.5f * r;
    float p = 0.00392377f;
    p = fmaf(p, u, -0.01647633f);
    p = fmaf(p, u, 0.02635537f);
    p = fmaf(p, u, -0.02057706f);
    p = fmaf(p, u, 0.0091628f);
    p = fmaf(p, u, -0.00157565f);
    p = fmaf(p, u, 0.00225319f);
    p = fmaf(p, u, 0.01328592f);
    p = fmaf(p, u, 0.39894228f);
    return __builtin_amdgcn_sqrtf(2.0f * r) * p;
}

#define PHI_F_75 0.21445709f   // phi_f(7.5)

__device__ __forceinline__ float phi_eval(float s) {
    // phi(x) = phi_f(min(x,a)) - phi_f(a) + phi_g(max(x,a)) : both branches always summed
    float f = phi_f_eval(fminf(s, 7.5f));
    float g = phi_g_eval(fmaxf(s, 7.5f));
    return f - PHI_F_75 + g;
}

__device__ __forceinline__ float fast_tanh(float x) {
    float e = __expf(2.0f * x);
    float r = __builtin_amdgcn_rcpf(e + 1.0f);
    return fmaf(-2.0f, r, 1.0f);   // 1 - 2/(e^{2x}+1); saturates correctly at +-1
}

__device__ __forceinline__ float waveReduce(float v) {
    v += __shfl_down(v, 32, 64);
    v += __shfl_down(v, 16, 64);
    v += __shfl_down(v, 8, 64);
    v += __shfl_down(v, 4, 64);
    v += __shfl_down(v, 2, 64);
    v += __shfl_down(v, 1, 64);
    return v;   // valid in lane 0
}

// -------- LDS layout (floats) for MLP kernel --------
#define O_W1T   0       // [32][64]
#define O_W2T   2048    // [16][32]
#define O_WD2T  2560    // [32][16]
#define O_WD3T  3072    // [64][32]
#define O_W3T   5120    // [2][16]
#define O_WD1T  5152    // [16][2]
#define O_B1    5184
#define O_B2    5216
#define O_B3    5232
#define O_BD1   5236
#define O_BD2   5252
#define O_BD3   5284
#define O_MU    5348    // 20
#define O_VAR   5368    // 10
#define O_PRB   5378    // 10
#define SM_TOT  5392

// Kernel 1: per-row MLP (one row per lane), writes z, and per-block partials of
// rec_loss sum, B-term sum, class-CE sum, label sum.
__global__ __launch_bounds__(64, 1) void k_mlp(
    const float* __restrict__ batch,
    const float* __restrict__ We1, const float* __restrict__ be1,
    const float* __restrict__ We2, const float* __restrict__ be2,
    const float* __restrict__ We3, const float* __restrict__ be3,
    const float* __restrict__ Wd1, const float* __restrict__ bd1,
    const float* __restrict__ Wd2, const float* __restrict__ bd2,
    const float* __restrict__ Wd3, const float* __restrict__ bd3,
    const float* __restrict__ means, const float* __restrict__ vars,
    const float* __restrict__ probs,
    float2* __restrict__ zbuf,
    float* __restrict__ recp, float* __restrict__ Bp,
    float* __restrict__ clsp, float* __restrict__ labp,
    float gamma)
{
    __shared__ __align__(16) float sm[SM_TOT];
    const int tid = threadIdx.x;

    // stage transposed weights into LDS
    for (int idx = tid; idx < 2048; idx += 64) { int i = idx >> 5, j = idx & 31; sm[O_W1T + j * 64 + i] = We1[idx]; }
    for (int idx = tid; idx < 512;  idx += 64) { int i = idx >> 4, j = idx & 15; sm[O_W2T + j * 32 + i] = We2[idx]; }
    for (int idx = tid; idx < 512;  idx += 64) { int i = idx >> 5, j = idx & 31; sm[O_WD2T + j * 16 + i] = Wd2[idx]; }
    for (int idx = tid; idx < 2048; idx += 64) { int i = idx >> 6, j = idx & 63; sm[O_WD3T + j * 32 + i] = Wd3[idx]; }
    if (tid < 32) { int i = tid >> 1, j = tid & 1;  sm[O_W3T + j * 16 + i] = We3[tid]; }
    else          { int t2 = tid - 32; int i = t2 >> 4, j = t2 & 15; sm[O_WD1T + j * 2 + i] = Wd1[t2]; }
    if (tid < 32) sm[O_B1 + tid] = be1[tid];
    if (tid < 16) sm[O_B2 + tid] = be2[tid];
    if (tid < 2)  sm[O_B3 + tid] = be3[tid];
    if (tid < 16) sm[O_BD1 + tid] = bd1[tid];
    if (tid < 32) sm[O_BD2 + tid] = bd2[tid];
    { // bd3: 64
        sm[O_BD3 + tid] = bd3[tid];
    }
    if (tid < 20) sm[O_MU + tid] = means[tid];
    if (tid < 10) sm[O_VAR + tid] = vars[tid];
    if (tid < 10) sm[O_PRB + tid] = probs[tid];
    __syncthreads();

    const int row = blockIdx.x * 64 + tid;
    const float* rp = batch + (size_t)row * ROW_STRIDE;

    float tau[64];
#pragma unroll
    for (int i = 0; i < 32; i++) {
        float2 v = ((const float2*)rp)[i];
        tau[2 * i] = v.x; tau[2 * i + 1] = v.y;
    }

    // layer 1: 64 -> 32, tanh
    float x1[32];
#pragma unroll
    for (int j = 0; j < 32; j++) {
        const float4* w = (const float4*)&sm[O_W1T + j * 64];
        float acc = sm[O_B1 + j];
#pragma unroll
        for (int i = 0; i < 16; i++) {
            float4 wv = w[i];
            acc = fmaf(tau[4 * i],     wv.x, acc);
            acc = fmaf(tau[4 * i + 1], wv.y, acc);
            acc = fmaf(tau[4 * i + 2], wv.z, acc);
            acc = fmaf(tau[4 * i + 3], wv.w, acc);
        }
        x1[j] = fast_tanh(acc);
    }

    // layer 2: 32 -> 16, tanh
    float x2[16];
#pragma unroll
    for (int j = 0; j < 16; j++) {
        const float4* w = (const float4*)&sm[O_W2T + j * 32];
        float acc = sm[O_B2 + j];
#pragma unroll
        for (int i = 0; i < 8; i++) {
            float4 wv = w[i];
            acc = fmaf(x1[4 * i],     wv.x, acc);
            acc = fmaf(x1[4 * i + 1], wv.y, acc);
            acc = fmaf(x1[4 * i + 2], wv.z, acc);
            acc = fmaf(x1[4 * i + 3], wv.w, acc);
        }
        x2[j] = fast_tanh(acc);
    }

    // layer 3: 16 -> 2 (z, linear)
    float z0 = sm[O_B3 + 0], z1 = sm[O_B3 + 1];
#pragma unroll
    for (int i = 0; i < 16; i++) {
        z0 = fmaf(x2[i], sm[O_W3T + 0 * 16 + i], z0);
        z1 = fmaf(x2[i], sm[O_W3T + 1 * 16 + i], z1);
    }
    zbuf[row] = make_float2(z0, z1);

    // decoder layer 1: 2 -> 16, tanh
    float h1[16];
#pragma unroll
    for (int j = 0; j < 16; j++) {
        float acc = sm[O_BD1 + j];
        acc = fmaf(z0, sm[O_WD1T + j * 2 + 0], acc);
        acc = fmaf(z1, sm[O_WD1T + j * 2 + 1], acc);
        h1[j] = fast_tanh(acc);
    }

    // decoder layer 2: 16 -> 32, tanh
    float h2[32];
#pragma unroll
    for (int j = 0; j < 32; j++) {
        const float4* w = (const float4*)&sm[O_WD2T + j * 16];
        float acc = sm[O_BD2 + j];
#pragma unroll
        for (int i = 0; i < 4; i++) {
            float4 wv = w[i];
            acc = fmaf(h1[4 * i],     wv.x, acc);
            acc = fmaf(h1[4 * i + 1], wv.y, acc);
            acc = fmaf(h1[4 * i + 2], wv.z, acc);
            acc = fmaf(h1[4 * i + 3], wv.w, acc);
        }
        h2[j] = fast_tanh(acc);
    }

    // decoder layer 3: 32 -> 64 + rec loss
    float rec = 0.0f;
#pragma unroll
    for (int o = 0; o < 64; o++) {
        const float4* w = (const float4*)&sm[O_WD3T + o * 32];
        float acc = sm[O_BD3 + o];
#pragma unroll
        for (int i = 0; i < 8; i++) {
            float4 wv = w[i];
            acc = fmaf(h2[4 * i],     wv.x, acc);
            acc = fmaf(h2[4 * i + 1], wv.y, acc);
            acc = fmaf(h2[4 * i + 2], wv.z, acc);
            acc = fmaf(h2[4 * i + 3], wv.w, acc);
        }
        float e = acc - tau[o];
        rec = fmaf(e, e, rec);
    }

    // class logits + B term
    const float two_g = 2.0f * gamma;
    const float inv_m = 1.0f / (float)M_ROWS;
    float lg[NCLS];
    float mx = -3.0e38f;
    float Bacc = 0.0f;
#pragma unroll
    for (int c = 0; c < NCLS; c++) {
        float d0 = z0 - sm[O_MU + 2 * c];
        float d1 = z1 - sm[O_MU + 2 * c + 1];
        float sqc = fmaf(d0, d0, d1 * d1);
        float vc = sm[O_VAR + c];
        float lgc = __logf(sm[O_PRB + c]) - __logf(TWO_PI_F * vc)
                    - sqc * 0.5f * __builtin_amdgcn_rcpf(vc);
        lg[c] = lgc;
        mx = fmaxf(mx, lgc);

        float den = vc + two_g;
        float sB = sqc * 0.5f * __builtin_amdgcn_rcpf(den);
        float coef = 2.0f * inv_m * sm[O_PRB + c] * __builtin_amdgcn_rsqf(TWO_PI_F * den);
        Bacc = fmaf(coef, phi_eval(sB), Bacc);
    }
    float esum = 0.0f;
#pragma unroll
    for (int c = 0; c < NCLS; c++) esum += __expf(lg[c] - mx);
    float lse = __logf(esum) + mx;

    float suml = 0.0f, ce = 0.0f;
#pragma unroll
    for (int c = 0; c < NCLS; c++) {
        float lb = rp[IN_DIM + c];
        suml += lb;
        ce = fmaf(lb, lse - lg[c], ce);
    }
    float cls = (suml == 1.0f) ? ce : 0.0f;

    // per-block (one wave) reductions -> partial arrays
    float r0 = waveReduce(rec);
    float r1 = waveReduce(Bacc);
    float r2 = waveReduce(cls);
    float r3 = waveReduce(suml);
    if (tid == 0) {
        recp[blockIdx.x] = r0;
        Bp[blockIdx.x]   = r1;
        clsp[blockIdx.x] = r2;
        labp[blockIdx.x] = r3;
    }
}

// Kernel 2: pairwise A term over upper-triangular 64x64 tiles.
__global__ __launch_bounds__(64, 1) void k_pair(
    const float2* __restrict__ z, float* __restrict__ Apart, float inv4g)
{
    const int ti = blockIdx.x, tj = blockIdx.y;
    const int bid = blockIdx.x + gridDim.x * blockIdx.y;
    const int lane = threadIdx.x;
    if (tj < ti) {              // dead half: write 0 so no memset needed
        if (lane == 0) Apart[bid] = 0.0f;
        return;
    }
    __shared__ float2 zjs[64];
    const int i = ti * 64 + lane;
    float2 zi = z[i];
    zjs[lane] = z[tj * 64 + lane];
    __syncthreads();

    const bool offd = (ti != tj);
    float acc = 0.0f;
#pragma unroll 8
    for (int jj = 0; jj < 64; jj++) {
        float dx = zi.x - zjs[jj].x;
        float dy = zi.y - zjs[jj].y;
        float s = fmaf(dx, dx, dy * dy) * inv4g;
        float p = phi_eval(s);
        if (offd || (tj * 64 + jj) > i) acc += p;
    }
    float tot = waveReduce(acc);
    if (lane == 0) Apart[bid] = tot;   // raw sum over pairs i<j in this tile
}

// Kernel 3: finalize — C term, reduce partials, assemble scalar.
__global__ __launch_bounds__(256) void k_fin(
    const float* __restrict__ means, const float* __restrict__ vars,
    const float* __restrict__ probs,
    const float* __restrict__ Apart,
    const float* __restrict__ recp, const float* __restrict__ Bp,
    const float* __restrict__ clsp, const float* __restrict__ labp,
    float* __restrict__ out, float gamma)
{
    __shared__ double sA[256];
    __shared__ double s4[256];
    __shared__ float cbuf[256];
    const int t = threadIdx.x;

    // C term: 100 ordered class pairs
    float cval = 0.0f;
    if (t < 100) {
        int ci = t / 10, cj = t - 10 * (t / 10);
        float vm = vars[ci] + vars[cj];
        float d0 = means[2 * ci] - means[2 * cj];
        float d1 = means[2 * ci + 1] - means[2 * cj + 1];
        float c1 = fmaf(d0, d0, d1 * d1);
        float s = c1 / (2.0f * vm + 4.0f * gamma);
        float c2 = phi_eval(s);
        float c3 = probs[ci] * probs[cj] * __builtin_amdgcn_rsqf(TWO_PI_F * (vm + 2.0f * gamma));
        cval = c3 * c2;
    }
    cbuf[t] = cval;

    // A partial reduce: 4096 entries
    double av = 0.0;
#pragma unroll
    for (int k = 0; k < 16; k++) av += (double)Apart[t + 256 * k];
    sA[t] = av;

    // the four 64-entry partial arrays
    double pv;
    if (t < 64)       pv = (double)recp[t];
    else if (t < 128) pv = (double)Bp[t - 64];
    else if (t < 192) pv = (double)clsp[t - 128];
    else              pv = (double)labp[t - 192];
    s4[t] = pv;
    __syncthreads();

    if (t == 0) {
        double Asum = 0.0, C = 0.0, rec = 0.0, B = 0.0, cls = 0.0, lab = 0.0;
        for (int k = 0; k < 256; k++) Asum += sA[k];
        for (int k = 0; k < 256; k++) C += (double)cbuf[k];
        for (int k = 0; k < 64; k++)  rec += s4[k];
        for (int k = 64; k < 128; k++) B += s4[k];
        for (int k = 128; k < 192; k++) cls += s4[k];
        for (int k = 192; k < 256; k++) lab += s4[k];

        const double m = (double)M_ROWS;
        const double gam = (double)gamma;
        double phi0 = (double)phi_eval(0.0f);
        double Atot = 2.0 * Asum + m * phi0;                 // full i,j sum incl. diagonal
        double A = Atot / (m * m * sqrt(2.0 * M_PI * 2.0 * gam));
        double den = lab; if (den == 0.0) den = 1.0;
        double cw = A - B + C;
        double total = rec / (m * 64.0) + 8.0 + log(cw) + 2.0 * (cls / den);
        out[0] = (float)total;
    }
}

extern "C" void kernel_launch(void* const* d_in, const int* in_sizes, int n_in,
                              void* d_out, int out_size, void* d_ws, size_t ws_size,
                              hipStream_t stream) {
    (void)in_sizes; (void)n_in; (void)out_size; (void)ws_size;
    const float* batch = (const float*)d_in[0];
    const float* We1 = (const float*)d_in[1];
    const float* be1 = (const float*)d_in[2];
    const float* We2 = (const float*)d_in[3];
    const float* be2 = (const float*)d_in[4];
    const float* We3 = (const float*)d_in[5];
    const float* be3 = (const float*)d_in[6];
    const float* Wd1 = (const float*)d_in[7];
    const float* bd1 = (const float*)d_in[8];
    const float* Wd2 = (const float*)d_in[9];
    const float* bd2 = (const float*)d_in[10];
    const float* Wd3 = (const float*)d_in[11];
    const float* bd3 = (const float*)d_in[12];
    const float* means = (const float*)d_in[13];
    const float* vars = (const float*)d_in[14];
    const float* probs = (const float*)d_in[15];

    float* ws = (float*)d_ws;
    float2* zbuf = (float2*)ws;          // 4096 float2 = 8192 floats
    float* Apart = ws + 8192;            // 4096 floats
    float* recp  = ws + 12288;           // 64
    float* Bp    = ws + 12352;           // 64
    float* clsp  = ws + 12416;           // 64
    float* labp  = ws + 12480;           // 64

    const float gamma = (float)pow(4.0 / (3.0 * (double)M_ROWS), 0.2);
    const float inv4g = 1.0f / (4.0f * gamma);

    k_mlp<<<64, 64, 0, stream>>>(batch, We1, be1, We2, be2, We3, be3,
                                 Wd1, bd1, Wd2, bd2, Wd3, bd3,
                                 means, vars, probs,
                                 zbuf, recp, Bp, clsp, labp, gamma);
    k_pair<<<dim3(64, 64), 64, 0, stream>>>(zbuf, Apart, inv4g);
    k_fin<<<1, 256, 0, stream>>>(means, vars, probs, Apart, recp, Bp, clsp, labp,
                                 (float*)d_out, gamma);
}

// Round 3
// 131.386 us; speedup vs baseline: 1.0706x; 1.0706x over previous
//
#include <hip/hip_runtime.h>
#include <math.h>

#define M_ROWS 4096
#define IN_DIM 64
#define NCLS 10
#define ROW_STRIDE 74   // 64 tau + 10 labels
#define TWO_PI_F 6.283185307179586f
#define NTILE 64        // 4096/64 row tiles
#define NPAIR 2080      // 64*65/2 upper-triangular tile pairs

// ---------------- phi (Bessel-I0-based) ----------------
__device__ __forceinline__ float phi_f_eval(float s) {
    // s in [0, 7.5]
    float t = s * (1.0f / 7.5f);
    float t2 = t * t;
    float p = 0.0045813f;
    p = fmaf(p, t2, 0.0360768f);
    p = fmaf(p, t2, 0.2659732f);
    p = fmaf(p, t2, 1.2067492f);
    p = fmaf(p, t2, 3.0899424f);
    p = fmaf(p, t2, 3.5156229f);
    p = fmaf(p, t2, 1.0f);
    return __expf(-0.5f * s) * p;
}

__device__ __forceinline__ float phi_g_eval(float s) {
    // s >= 7.5
    float r = __builtin_amdgcn_rcpf(s);
    float u = 7.5f * r;
    float p = 0.00392377f;
    p = fmaf(p, u, -0.01647633f);
    p = fmaf(p, u, 0.02635537f);
    p = fmaf(p, u, -0.02057706f);
    p = fmaf(p, u, 0.0091628f);
    p = fmaf(p, u, -0.00157565f);
    p = fmaf(p, u, 0.00225319f);
    p = fmaf(p, u, 0.01328592f);
    p = fmaf(p, u, 0.39894228f);
    return __builtin_amdgcn_sqrtf(2.0f * r) * p;
}

#define PHI_F_75 0.21445709f   // phi_f(7.5)

__device__ __forceinline__ float phi_eval(float s) {
    // phi(x) = phi_f(min(x,a)) - phi_f(a) + phi_g(max(x,a)) : both branches always summed
    float f = phi_f_eval(fminf(s, 7.5f));
    float g = phi_g_eval(fmaxf(s, 7.5f));
    return f - PHI_F_75 + g;
}

__device__ __forceinline__ float fast_tanh(float x) {
    float e = __expf(2.0f * x);
    float r = __builtin_amdgcn_rcpf(e + 1.0f);
    return fmaf(-2.0f, r, 1.0f);   // 1 - 2/(e^{2x}+1); saturates correctly at +-1
}

__device__ __forceinline__ float waveReduce(float v) {
    v += __shfl_down(v, 32, 64);
    v += __shfl_down(v, 16, 64);
    v += __shfl_down(v, 8, 64);
    v += __shfl_down(v, 4, 64);
    v += __shfl_down(v, 2, 64);
    v += __shfl_down(v, 1, 64);
    return v;   // valid in lane 0
}

__device__ __forceinline__ double waveReduceD(double v) {
    v += __shfl_down(v, 32, 64);
    v += __shfl_down(v, 16, 64);
    v += __shfl_down(v, 8, 64);
    v += __shfl_down(v, 4, 64);
    v += __shfl_down(v, 2, 64);
    v += __shfl_down(v, 1, 64);
    return v;   // valid in lane 0 of each wave
}

// -------- LDS layout (floats) for MLP kernel --------
#define O_W1T   0       // [32][64]
#define O_W2T   2048    // [16][32]
#define O_WD2T  2560    // [32][16]
#define O_WD3T  3072    // [64][32]
#define O_W3T   5120    // [2][16]
#define O_WD1T  5152    // [16][2]
#define O_B1    5184
#define O_B2    5216
#define O_B3    5232
#define O_BD1   5236
#define O_BD2   5252
#define O_BD3   5284
#define O_MU    5348    // 20
#define O_VAR   5368    // 10
#define O_PRB   5378    // 10
#define SM_TOT  5392

// Kernel 1: per-row MLP (one row per lane), writes z, and per-block partials of
// rec_loss sum, B-term sum, class-CE sum, label sum. Verified bit-exact in R1.
__global__ __launch_bounds__(64, 1) void k_mlp(
    const float* __restrict__ batch,
    const float* __restrict__ We1, const float* __restrict__ be1,
    const float* __restrict__ We2, const float* __restrict__ be2,
    const float* __restrict__ We3, const float* __restrict__ be3,
    const float* __restrict__ Wd1, const float* __restrict__ bd1,
    const float* __restrict__ Wd2, const float* __restrict__ bd2,
    const float* __restrict__ Wd3, const float* __restrict__ bd3,
    const float* __restrict__ means, const float* __restrict__ vars,
    const float* __restrict__ probs,
    float2* __restrict__ zbuf,
    float* __restrict__ recp, float* __restrict__ Bp,
    float* __restrict__ clsp, float* __restrict__ labp,
    float gamma)
{
    __shared__ __align__(16) float sm[SM_TOT];
    const int tid = threadIdx.x;

    // stage transposed weights into LDS
    for (int idx = tid; idx < 2048; idx += 64) { int i = idx >> 5, j = idx & 31; sm[O_W1T + j * 64 + i] = We1[idx]; }
    for (int idx = tid; idx < 512;  idx += 64) { int i = idx >> 4, j = idx & 15; sm[O_W2T + j * 32 + i] = We2[idx]; }
    for (int idx = tid; idx < 512;  idx += 64) { int i = idx >> 5, j = idx & 31; sm[O_WD2T + j * 16 + i] = Wd2[idx]; }
    for (int idx = tid; idx < 2048; idx += 64) { int i = idx >> 6, j = idx & 63; sm[O_WD3T + j * 32 + i] = Wd3[idx]; }
    if (tid < 32) { int i = tid >> 1, j = tid & 1;  sm[O_W3T + j * 16 + i] = We3[tid]; }
    else          { int t2 = tid - 32; int i = t2 >> 4, j = t2 & 15; sm[O_WD1T + j * 2 + i] = Wd1[t2]; }
    if (tid < 32) sm[O_B1 + tid] = be1[tid];
    if (tid < 16) sm[O_B2 + tid] = be2[tid];
    if (tid < 2)  sm[O_B3 + tid] = be3[tid];
    if (tid < 16) sm[O_BD1 + tid] = bd1[tid];
    if (tid < 32) sm[O_BD2 + tid] = bd2[tid];
    sm[O_BD3 + tid] = bd3[tid];
    if (tid < 20) sm[O_MU + tid] = means[tid];
    if (tid < 10) sm[O_VAR + tid] = vars[tid];
    if (tid < 10) sm[O_PRB + tid] = probs[tid];
    __syncthreads();

    const int row = blockIdx.x * 64 + tid;
    const float* rp = batch + (size_t)row * ROW_STRIDE;

    float tau[64];
#pragma unroll
    for (int i = 0; i < 32; i++) {
        float2 v = ((const float2*)rp)[i];
        tau[2 * i] = v.x; tau[2 * i + 1] = v.y;
    }

    // layer 1: 64 -> 32, tanh
    float x1[32];
#pragma unroll
    for (int j = 0; j < 32; j++) {
        const float4* w = (const float4*)&sm[O_W1T + j * 64];
        float acc = sm[O_B1 + j];
#pragma unroll
        for (int i = 0; i < 16; i++) {
            float4 wv = w[i];
            acc = fmaf(tau[4 * i],     wv.x, acc);
            acc = fmaf(tau[4 * i + 1], wv.y, acc);
            acc = fmaf(tau[4 * i + 2], wv.z, acc);
            acc = fmaf(tau[4 * i + 3], wv.w, acc);
        }
        x1[j] = fast_tanh(acc);
    }

    // layer 2: 32 -> 16, tanh
    float x2[16];
#pragma unroll
    for (int j = 0; j < 16; j++) {
        const float4* w = (const float4*)&sm[O_W2T + j * 32];
        float acc = sm[O_B2 + j];
#pragma unroll
        for (int i = 0; i < 8; i++) {
            float4 wv = w[i];
            acc = fmaf(x1[4 * i],     wv.x, acc);
            acc = fmaf(x1[4 * i + 1], wv.y, acc);
            acc = fmaf(x1[4 * i + 2], wv.z, acc);
            acc = fmaf(x1[4 * i + 3], wv.w, acc);
        }
        x2[j] = fast_tanh(acc);
    }

    // layer 3: 16 -> 2 (z, linear)
    float z0 = sm[O_B3 + 0], z1 = sm[O_B3 + 1];
#pragma unroll
    for (int i = 0; i < 16; i++) {
        z0 = fmaf(x2[i], sm[O_W3T + 0 * 16 + i], z0);
        z1 = fmaf(x2[i], sm[O_W3T + 1 * 16 + i], z1);
    }
    zbuf[row] = make_float2(z0, z1);

    // decoder layer 1: 2 -> 16, tanh
    float h1[16];
#pragma unroll
    for (int j = 0; j < 16; j++) {
        float acc = sm[O_BD1 + j];
        acc = fmaf(z0, sm[O_WD1T + j * 2 + 0], acc);
        acc = fmaf(z1, sm[O_WD1T + j * 2 + 1], acc);
        h1[j] = fast_tanh(acc);
    }

    // decoder layer 2: 16 -> 32, tanh
    float h2[32];
#pragma unroll
    for (int j = 0; j < 32; j++) {
        const float4* w = (const float4*)&sm[O_WD2T + j * 16];
        float acc = sm[O_BD2 + j];
#pragma unroll
        for (int i = 0; i < 4; i++) {
            float4 wv = w[i];
            acc = fmaf(h1[4 * i],     wv.x, acc);
            acc = fmaf(h1[4 * i + 1], wv.y, acc);
            acc = fmaf(h1[4 * i + 2], wv.z, acc);
            acc = fmaf(h1[4 * i + 3], wv.w, acc);
        }
        h2[j] = fast_tanh(acc);
    }

    // decoder layer 3: 32 -> 64 + rec loss
    float rec = 0.0f;
#pragma unroll
    for (int o = 0; o < 64; o++) {
        const float4* w = (const float4*)&sm[O_WD3T + o * 32];
        float acc = sm[O_BD3 + o];
#pragma unroll
        for (int i = 0; i < 8; i++) {
            float4 wv = w[i];
            acc = fmaf(h2[4 * i],     wv.x, acc);
            acc = fmaf(h2[4 * i + 1], wv.y, acc);
            acc = fmaf(h2[4 * i + 2], wv.z, acc);
            acc = fmaf(h2[4 * i + 3], wv.w, acc);
        }
        float e = acc - tau[o];
        rec = fmaf(e, e, rec);
    }

    // class logits + B term
    const float two_g = 2.0f * gamma;
    const float inv_m = 1.0f / (float)M_ROWS;
    float lg[NCLS];
    float mx = -3.0e38f;
    float Bacc = 0.0f;
#pragma unroll
    for (int c = 0; c < NCLS; c++) {
        float d0 = z0 - sm[O_MU + 2 * c];
        float d1 = z1 - sm[O_MU + 2 * c + 1];
        float sqc = fmaf(d0, d0, d1 * d1);
        float vc = sm[O_VAR + c];
        float lgc = __logf(sm[O_PRB + c]) - __logf(TWO_PI_F * vc)
                    - sqc * 0.5f * __builtin_amdgcn_rcpf(vc);
        lg[c] = lgc;
        mx = fmaxf(mx, lgc);

        float den = vc + two_g;
        float sB = sqc * 0.5f * __builtin_amdgcn_rcpf(den);
        float coef = 2.0f * inv_m * sm[O_PRB + c] * __builtin_amdgcn_rsqf(TWO_PI_F * den);
        Bacc = fmaf(coef, phi_eval(sB), Bacc);
    }
    float esum = 0.0f;
#pragma unroll
    for (int c = 0; c < NCLS; c++) esum += __expf(lg[c] - mx);
    float lse = __logf(esum) + mx;

    float suml = 0.0f, ce = 0.0f;
#pragma unroll
    for (int c = 0; c < NCLS; c++) {
        float lb = rp[IN_DIM + c];
        suml += lb;
        ce = fmaf(lb, lse - lg[c], ce);
    }
    float cls = (suml == 1.0f) ? ce : 0.0f;

    // per-block (one wave) reductions -> partial arrays
    float r0 = waveReduce(rec);
    float r1 = waveReduce(Bacc);
    float r2 = waveReduce(cls);
    float r3 = waveReduce(suml);
    if (tid == 0) {
        recp[blockIdx.x] = r0;
        Bp[blockIdx.x]   = r1;
        clsp[blockIdx.x] = r2;
        labp[blockIdx.x] = r3;
    }
}

// Kernel 2: pairwise A term. Exactly NPAIR blocks, one upper-triangular 64x64
// tile each; no dead blocks, no inner-loop predicate. Diagonal tiles summed
// once (they include the i==j elements); off-diagonal tiles weighted x2, so
// sum(Apart) == full ordered-pair sum including the diagonal.
__global__ __launch_bounds__(64, 4) void k_pair(
    const float2* __restrict__ z, float* __restrict__ Apart, float inv4g)
{
    const int p = blockIdx.x;
    // triangular decode: p = tj*(tj+1)/2 + ti, ti <= tj
    int tj = (int)((__builtin_amdgcn_sqrtf(8.0f * (float)p + 1.0f) - 1.0f) * 0.5f);
    while ((tj + 1) * (tj + 2) / 2 <= p) tj++;
    while (tj * (tj + 1) / 2 > p) tj--;
    const int ti = p - tj * (tj + 1) / 2;

    const int lane = threadIdx.x;
    __shared__ float2 zjs[64];
    float2 zi = z[ti * 64 + lane];
    zjs[lane] = z[tj * 64 + lane];
    __syncthreads();

    float acc0 = 0.0f, acc1 = 0.0f;
#pragma unroll 8
    for (int jj = 0; jj < 64; jj += 2) {
        float2 a = zjs[jj], b = zjs[jj + 1];
        float dx0 = zi.x - a.x, dy0 = zi.y - a.y;
        float dx1 = zi.x - b.x, dy1 = zi.y - b.y;
        acc0 += phi_eval(fmaf(dx0, dx0, dy0 * dy0) * inv4g);
        acc1 += phi_eval(fmaf(dx1, dx1, dy1 * dy1) * inv4g);
    }
    float tot = waveReduce(acc0 + acc1);
    if (lane == 0) Apart[p] = (ti == tj) ? tot : 2.0f * tot;
}

// Kernel 3: finalize — C term + reductions via per-wave double shuffles.
// 256 threads = 4 waves; wave w owns partial-array segment w exactly, so no
// LDS tree (the R2 LDS tree was OOB/cross-segment — this replaces it).
__global__ __launch_bounds__(256) void k_fin(
    const float* __restrict__ means, const float* __restrict__ vars,
    const float* __restrict__ probs,
    const float* __restrict__ Apart,
    const float* __restrict__ recp, const float* __restrict__ Bp,
    const float* __restrict__ clsp, const float* __restrict__ labp,
    float* __restrict__ out, float gamma)
{
    __shared__ double wsum[8];
    const int t = threadIdx.x;
    const int w = t >> 6;

    const double m = (double)M_ROWS;
    const double gam = (double)gamma;
    const double invA = 1.0 / (m * m * sqrt(2.0 * M_PI * 2.0 * gam));

    // A partials (diagonal-inclusive, pre-weighted)
    double av = 0.0;
#pragma unroll
    for (int k = 0; k < 9; k++) {
        int idx = t + 256 * k;
        if (idx < NPAIR) av += (double)Apart[idx];
    }

    // C term: 100 ordered class pairs
    double cv = 0.0;
    if (t < 100) {
        int ci = t / 10, cj = t - 10 * (t / 10);
        float vm = vars[ci] + vars[cj];
        float d0 = means[2 * ci] - means[2 * cj];
        float d1 = means[2 * ci + 1] - means[2 * cj + 1];
        float c1 = fmaf(d0, d0, d1 * d1);
        float s = c1 / (2.0f * vm + 4.0f * gamma);
        float c2 = phi_eval(s);
        float c3 = probs[ci] * probs[cj] * __builtin_amdgcn_rsqf(TWO_PI_F * (vm + 2.0f * gamma));
        cv = (double)(c3 * c2);
    }

    // per-wave reduce of the (A+C) contribution
    double acw = waveReduceD(av * invA + cv);

    // four 64-entry partial arrays: wave w reduces array w
    const int l = t & 63;
    double pv;
    if (w == 0)      pv = (double)recp[l];
    else if (w == 1) pv = (double)Bp[l];
    else if (w == 2) pv = (double)clsp[l];
    else             pv = (double)labp[l];
    double pw = waveReduceD(pv);

    if (l == 0) { wsum[w] = acw; wsum[4 + w] = pw; }
    __syncthreads();

    if (t == 0) {
        double AC = wsum[0] + wsum[1] + wsum[2] + wsum[3];
        double rec = wsum[4], B = wsum[5], cls = wsum[6], lab = wsum[7];
        double den = (lab == 0.0) ? 1.0 : lab;
        double cw = AC - B;
        double total = rec / (m * 64.0) + 8.0 + log(cw) + 2.0 * (cls / den);
        out[0] = (float)total;
    }
}

extern "C" void kernel_launch(void* const* d_in, const int* in_sizes, int n_in,
                              void* d_out, int out_size, void* d_ws, size_t ws_size,
                              hipStream_t stream) {
    (void)in_sizes; (void)n_in; (void)out_size; (void)ws_size;
    const float* batch = (const float*)d_in[0];
    const float* We1 = (const float*)d_in[1];
    const float* be1 = (const float*)d_in[2];
    const float* We2 = (const float*)d_in[3];
    const float* be2 = (const float*)d_in[4];
    const float* We3 = (const float*)d_in[5];
    const float* be3 = (const float*)d_in[6];
    const float* Wd1 = (const float*)d_in[7];
    const float* bd1 = (const float*)d_in[8];
    const float* Wd2 = (const float*)d_in[9];
    const float* bd2 = (const float*)d_in[10];
    const float* Wd3 = (const float*)d_in[11];
    const float* bd3 = (const float*)d_in[12];
    const float* means = (const float*)d_in[13];
    const float* vars = (const float*)d_in[14];
    const float* probs = (const float*)d_in[15];

    float* ws = (float*)d_ws;
    float2* zbuf = (float2*)ws;          // 4096 float2 = 8192 floats
    float* Apart = ws + 8192;            // 2080 floats
    float* recp  = ws + 12288;           // 64
    float* Bp    = ws + 12352;           // 64
    float* clsp  = ws + 12416;           // 64
    float* labp  = ws + 12480;           // 64

    const float gamma = (float)pow(4.0 / (3.0 * (double)M_ROWS), 0.2);
    const float inv4g = 1.0f / (4.0f * gamma);

    k_mlp<<<64, 64, 0, stream>>>(batch, We1, be1, We2, be2, We3, be3,
                                 Wd1, bd1, Wd2, bd2, Wd3, bd3,
                                 means, vars, probs,
                                 zbuf, recp, Bp, clsp, labp, gamma);
    k_pair<<<NPAIR, 64, 0, stream>>>(zbuf, Apart, inv4g);
    k_fin<<<1, 256, 0, stream>>>(means, vars, probs, Apart, recp, Bp, clsp, labp,
                                 (float*)d_out, gamma);
}

// Round 4
// 116.931 us; speedup vs baseline: 1.2030x; 1.1236x over previous
//
#include <hip/hip_runtime.h>
#include <math.h>

#define M_ROWS 4096
#define IN_DIM 64
#define NCLS 10
#define ROW_STRIDE 74   // 64 tau + 10 labels
#define TWO_PI_F 6.283185307179586f
#define NTILE 64
#define NPAIR 2080      // 64*65/2 upper-triangular tile pairs
#define NBLK_MLP 256    // 16 rows per block, 4 lanes (roles) per row

// ---------------- phi (Bessel-I0-based) ----------------
__device__ __forceinline__ float phi_f_eval(float s) {
    float t = s * (1.0f / 7.5f);
    float t2 = t * t;
    float p = 0.0045813f;
    p = fmaf(p, t2, 0.0360768f);
    p = fmaf(p, t2, 0.2659732f);
    p = fmaf(p, t2, 1.2067492f);
    p = fmaf(p, t2, 3.0899424f);
    p = fmaf(p, t2, 3.5156229f);
    p = fmaf(p, t2, 1.0f);
    return __expf(-0.5f * s) * p;
}

__device__ __forceinline__ float phi_g_eval(float s) {
    float r = __builtin_amdgcn_rcpf(s);
    float u = 7.5f * r;
    float p = 0.00392377f;
    p = fmaf(p, u, -0.01647633f);
    p = fmaf(p, u, 0.02635537f);
    p = fmaf(p, u, -0.02057706f);
    p = fmaf(p, u, 0.0091628f);
    p = fmaf(p, u, -0.00157565f);
    p = fmaf(p, u, 0.00225319f);
    p = fmaf(p, u, 0.01328592f);
    p = fmaf(p, u, 0.39894228f);
    return __builtin_amdgcn_sqrtf(2.0f * r) * p;
}

#define PHI_F_75 0.21445709f   // phi_f(7.5)

__device__ __forceinline__ float phi_eval(float s) {
    float f = phi_f_eval(fminf(s, 7.5f));
    float g = phi_g_eval(fmaxf(s, 7.5f));
    return f - PHI_F_75 + g;
}

__device__ __forceinline__ float fast_tanh(float x) {
    float e = __expf(2.0f * x);
    float r = __builtin_amdgcn_rcpf(e + 1.0f);
    return fmaf(-2.0f, r, 1.0f);
}

__device__ __forceinline__ float waveReduce(float v) {
    v += __shfl_down(v, 32, 64);
    v += __shfl_down(v, 16, 64);
    v += __shfl_down(v, 8, 64);
    v += __shfl_down(v, 4, 64);
    v += __shfl_down(v, 2, 64);
    v += __shfl_down(v, 1, 64);
    return v;
}

__device__ __forceinline__ double waveReduceD(double v) {
    v += __shfl_down(v, 32, 64);
    v += __shfl_down(v, 16, 64);
    v += __shfl_down(v, 8, 64);
    v += __shfl_down(v, 4, 64);
    v += __shfl_down(v, 2, 64);
    v += __shfl_down(v, 1, 64);
    return v;
}

// pick v_{r} from 4 candidates without dynamic register indexing (3 cndmasks)
__device__ __forceinline__ float sel4(float v0, float v1, float v2, float v3, int r) {
    float a = (r & 1) ? v1 : v0;
    float b = (r & 1) ? v3 : v2;
    return (r & 2) ? b : a;
}

// -------- LDS layout (floats), rows padded so 4 roles hit disjoint banks ----
#define P_W1   0        // 64 x (32 -> stride 36)
#define P_W2   2304     // 32 x (16 -> stride 20)
#define P_WD2  2944     // 16 x (32 -> stride 36)
#define P_WD3  3520     // 32 x (64 -> stride 68)
#define P_W3   5696     // 16x2 natural
#define P_WD1  5728     // 2x16 natural
#define P_B1   5760
#define P_B2   5792
#define P_B3   5808
#define P_BD1  5810
#define P_BD2  5826
#define P_BD3  5858
#define P_MU   5922
#define P_VAR  5942
#define P_PRB  5952
#define SMT    5962

// Kernel 1: MLP, 4 lanes per row. role r owns indices ≡ r (mod 4) of every
// layer dimension; partial dot-products reduced across roles via shfl_xor.
__global__ __launch_bounds__(64, 1) void k_mlp(
    const float* __restrict__ batch,
    const float* __restrict__ We1, const float* __restrict__ be1,
    const float* __restrict__ We2, const float* __restrict__ be2,
    const float* __restrict__ We3, const float* __restrict__ be3,
    const float* __restrict__ Wd1, const float* __restrict__ bd1,
    const float* __restrict__ Wd2, const float* __restrict__ bd2,
    const float* __restrict__ Wd3, const float* __restrict__ bd3,
    const float* __restrict__ means, const float* __restrict__ vars,
    const float* __restrict__ probs,
    float2* __restrict__ zbuf,
    float* __restrict__ recp, float* __restrict__ Bp,
    float* __restrict__ clsp, float* __restrict__ labp,
    float gamma)
{
    __shared__ __align__(16) float sm[SMT];
    const int tid = threadIdx.x;

    for (int idx = tid; idx < 2048; idx += 64) { int i = idx >> 5, j = idx & 31; sm[P_W1  + i * 36 + j] = We1[idx]; }
    for (int idx = tid; idx < 512;  idx += 64) { int i = idx >> 4, j = idx & 15; sm[P_W2  + i * 20 + j] = We2[idx]; }
    for (int idx = tid; idx < 512;  idx += 64) { int i = idx >> 5, j = idx & 31; sm[P_WD2 + i * 36 + j] = Wd2[idx]; }
    for (int idx = tid; idx < 2048; idx += 64) { int i = idx >> 6, j = idx & 63; sm[P_WD3 + i * 68 + j] = Wd3[idx]; }
    if (tid < 32) sm[P_W3 + tid] = We3[tid];
    else          sm[P_WD1 + tid - 32] = Wd1[tid - 32];
    if (tid < 32) sm[P_B1 + tid] = be1[tid];
    if (tid < 16) sm[P_B2 + tid] = be2[tid];
    if (tid < 2)  sm[P_B3 + tid] = be3[tid];
    if (tid < 16) sm[P_BD1 + tid] = bd1[tid];
    if (tid < 32) sm[P_BD2 + tid] = bd2[tid];
    sm[P_BD3 + tid] = bd3[tid];
    if (tid < 20) sm[P_MU + tid] = means[tid];
    if (tid < 10) sm[P_VAR + tid] = vars[tid];
    if (tid < 10) sm[P_PRB + tid] = probs[tid];
    __syncthreads();

    const int rw = tid & 15;         // row within block
    const int r  = tid >> 4;         // role 0..3
    const int row = blockIdx.x * 16 + rw;
    const float* rp = batch + (size_t)row * ROW_STRIDE;

    // tau elements this role owns: indices r + 4k
    float taus[16];
#pragma unroll
    for (int k = 0; k < 16; k++) taus[k] = rp[r + 4 * k];

    // ---- encoder L1: 64 -> 32 ----
    float a1[32];
#pragma unroll
    for (int j = 0; j < 32; j++) a1[j] = 0.0f;
#pragma unroll
    for (int k = 0; k < 16; k++) {
        const int i = r + 4 * k;
        const float4* wr = (const float4*)&sm[P_W1 + i * 36];
        const float ti = taus[k];
#pragma unroll
        for (int jj = 0; jj < 8; jj++) {
            float4 w = wr[jj];
            a1[4 * jj + 0] = fmaf(ti, w.x, a1[4 * jj + 0]);
            a1[4 * jj + 1] = fmaf(ti, w.y, a1[4 * jj + 1]);
            a1[4 * jj + 2] = fmaf(ti, w.z, a1[4 * jj + 2]);
            a1[4 * jj + 3] = fmaf(ti, w.w, a1[4 * jj + 3]);
        }
    }
#pragma unroll
    for (int j = 0; j < 32; j++) {
        a1[j] += __shfl_xor(a1[j], 16, 64);
        a1[j] += __shfl_xor(a1[j], 32, 64);
    }
    float x1own[8];
#pragma unroll
    for (int k = 0; k < 8; k++)
        x1own[k] = fast_tanh(sel4(a1[4 * k], a1[4 * k + 1], a1[4 * k + 2], a1[4 * k + 3], r)
                             + sm[P_B1 + r + 4 * k]);

    // ---- encoder L2: 32 -> 16 ----
    float a2[16];
#pragma unroll
    for (int j = 0; j < 16; j++) a2[j] = 0.0f;
#pragma unroll
    for (int k = 0; k < 8; k++) {
        const int i = r + 4 * k;
        const float4* wr = (const float4*)&sm[P_W2 + i * 20];
        const float x = x1own[k];
#pragma unroll
        for (int jj = 0; jj < 4; jj++) {
            float4 w = wr[jj];
            a2[4 * jj + 0] = fmaf(x, w.x, a2[4 * jj + 0]);
            a2[4 * jj + 1] = fmaf(x, w.y, a2[4 * jj + 1]);
            a2[4 * jj + 2] = fmaf(x, w.z, a2[4 * jj + 2]);
            a2[4 * jj + 3] = fmaf(x, w.w, a2[4 * jj + 3]);
        }
    }
#pragma unroll
    for (int j = 0; j < 16; j++) {
        a2[j] += __shfl_xor(a2[j], 16, 64);
        a2[j] += __shfl_xor(a2[j], 32, 64);
    }
    float x2own[4];
#pragma unroll
    for (int k = 0; k < 4; k++)
        x2own[k] = fast_tanh(sel4(a2[4 * k], a2[4 * k + 1], a2[4 * k + 2], a2[4 * k + 3], r)
                             + sm[P_B2 + r + 4 * k]);

    // ---- encoder L3: 16 -> 2 (z) ----
    float z0 = 0.0f, z1 = 0.0f;
#pragma unroll
    for (int k = 0; k < 4; k++) {
        const int i = r + 4 * k;
        z0 = fmaf(x2own[k], sm[P_W3 + 2 * i], z0);
        z1 = fmaf(x2own[k], sm[P_W3 + 2 * i + 1], z1);
    }
    z0 += __shfl_xor(z0, 16, 64); z0 += __shfl_xor(z0, 32, 64);
    z1 += __shfl_xor(z1, 16, 64); z1 += __shfl_xor(z1, 32, 64);
    z0 += sm[P_B3 + 0];
    z1 += sm[P_B3 + 1];
    if (r == 0) zbuf[row] = make_float2(z0, z1);

    // ---- decoder d1: 2 -> 16 ----
    float h1own[4];
#pragma unroll
    for (int k = 0; k < 4; k++) {
        const int j = r + 4 * k;
        float acc = sm[P_BD1 + j];
        acc = fmaf(z0, sm[P_WD1 + j], acc);
        acc = fmaf(z1, sm[P_WD1 + 16 + j], acc);
        h1own[k] = fast_tanh(acc);
    }

    // ---- decoder d2: 16 -> 32 ----
    float a3[32];
#pragma unroll
    for (int j = 0; j < 32; j++) a3[j] = 0.0f;
#pragma unroll
    for (int k = 0; k < 4; k++) {
        const int i = r + 4 * k;
        const float4* wr = (const float4*)&sm[P_WD2 + i * 36];
        const float x = h1own[k];
#pragma unroll
        for (int jj = 0; jj < 8; jj++) {
            float4 w = wr[jj];
            a3[4 * jj + 0] = fmaf(x, w.x, a3[4 * jj + 0]);
            a3[4 * jj + 1] = fmaf(x, w.y, a3[4 * jj + 1]);
            a3[4 * jj + 2] = fmaf(x, w.z, a3[4 * jj + 2]);
            a3[4 * jj + 3] = fmaf(x, w.w, a3[4 * jj + 3]);
        }
    }
#pragma unroll
    for (int j = 0; j < 32; j++) {
        a3[j] += __shfl_xor(a3[j], 16, 64);
        a3[j] += __shfl_xor(a3[j], 32, 64);
    }
    float h2own[8];
#pragma unroll
    for (int k = 0; k < 8; k++)
        h2own[k] = fast_tanh(sel4(a3[4 * k], a3[4 * k + 1], a3[4 * k + 2], a3[4 * k + 3], r)
                             + sm[P_BD2 + r + 4 * k]);

    // ---- decoder d3: 32 -> 64 + rec ----
    float a4[64];
#pragma unroll
    for (int j = 0; j < 64; j++) a4[j] = 0.0f;
#pragma unroll
    for (int k = 0; k < 8; k++) {
        const int i = r + 4 * k;
        const float4* wr = (const float4*)&sm[P_WD3 + i * 68];
        const float x = h2own[k];
#pragma unroll
        for (int jj = 0; jj < 16; jj++) {
            float4 w = wr[jj];
            a4[4 * jj + 0] = fmaf(x, w.x, a4[4 * jj + 0]);
            a4[4 * jj + 1] = fmaf(x, w.y, a4[4 * jj + 1]);
            a4[4 * jj + 2] = fmaf(x, w.z, a4[4 * jj + 2]);
            a4[4 * jj + 3] = fmaf(x, w.w, a4[4 * jj + 3]);
        }
    }
#pragma unroll
    for (int j = 0; j < 64; j++) {
        a4[j] += __shfl_xor(a4[j], 16, 64);
        a4[j] += __shfl_xor(a4[j], 32, 64);
    }
    float rec = 0.0f;
#pragma unroll
    for (int k = 0; k < 16; k++) {
        float dec = sel4(a4[4 * k], a4[4 * k + 1], a4[4 * k + 2], a4[4 * k + 3], r)
                    + sm[P_BD3 + r + 4 * k];
        float e = dec - taus[k];
        rec = fmaf(e, e, rec);
    }

    // ---- B term + class CE (all roles compute; zeroed for r != 0) ----
    const float two_g = 2.0f * gamma;
    const float inv_m = 1.0f / (float)M_ROWS;
    float lg[NCLS];
    float mx = -3.0e38f;
    float Bacc = 0.0f;
#pragma unroll
    for (int c = 0; c < NCLS; c++) {
        float d0 = z0 - sm[P_MU + 2 * c];
        float d1 = z1 - sm[P_MU + 2 * c + 1];
        float sqc = fmaf(d0, d0, d1 * d1);
        float vc = sm[P_VAR + c];
        float lgc = __logf(sm[P_PRB + c]) - __logf(TWO_PI_F * vc)
                    - sqc * 0.5f * __builtin_amdgcn_rcpf(vc);
        lg[c] = lgc;
        mx = fmaxf(mx, lgc);

        float den = vc + two_g;
        float sB = sqc * 0.5f * __builtin_amdgcn_rcpf(den);
        float coef = 2.0f * inv_m * sm[P_PRB + c] * __builtin_amdgcn_rsqf(TWO_PI_F * den);
        Bacc = fmaf(coef, phi_eval(sB), Bacc);
    }
    float esum = 0.0f;
#pragma unroll
    for (int c = 0; c < NCLS; c++) esum += __expf(lg[c] - mx);
    float lse = __logf(esum) + mx;

    float suml = 0.0f, ce = 0.0f;
#pragma unroll
    for (int c = 0; c < NCLS; c++) {
        float lb = rp[IN_DIM + c];
        suml += lb;
        ce = fmaf(lb, lse - lg[c], ce);
    }
    float cls = (suml == 1.0f) ? ce : 0.0f;
    if (r != 0) { Bacc = 0.0f; cls = 0.0f; suml = 0.0f; }

    float r0 = waveReduce(rec);
    float r1 = waveReduce(Bacc);
    float r2 = waveReduce(cls);
    float r3 = waveReduce(suml);
    if (tid == 0) {
        recp[blockIdx.x] = r0;
        Bp[blockIdx.x]   = r1;
        clsp[blockIdx.x] = r2;
        labp[blockIdx.x] = r3;
    }
}

// Kernel 2: pairwise A term (verified exact in R3). Triangular grid, diagonal
// tiles counted once, off-diagonal weighted x2.
__global__ __launch_bounds__(64, 4) void k_pair(
    const float2* __restrict__ z, float* __restrict__ Apart, float inv4g)
{
    const int p = blockIdx.x;
    int tj = (int)((__builtin_amdgcn_sqrtf(8.0f * (float)p + 1.0f) - 1.0f) * 0.5f);
    while ((tj + 1) * (tj + 2) / 2 <= p) tj++;
    while (tj * (tj + 1) / 2 > p) tj--;
    const int ti = p - tj * (tj + 1) / 2;

    const int lane = threadIdx.x;
    __shared__ float2 zjs[64];
    float2 zi = z[ti * 64 + lane];
    zjs[lane] = z[tj * 64 + lane];
    __syncthreads();

    float acc0 = 0.0f, acc1 = 0.0f;
#pragma unroll 8
    for (int jj = 0; jj < 64; jj += 2) {
        float2 a = zjs[jj], b = zjs[jj + 1];
        float dx0 = zi.x - a.x, dy0 = zi.y - a.y;
        float dx1 = zi.x - b.x, dy1 = zi.y - b.y;
        acc0 += phi_eval(fmaf(dx0, dx0, dy0 * dy0) * inv4g);
        acc1 += phi_eval(fmaf(dx1, dx1, dy1 * dy1) * inv4g);
    }
    float tot = waveReduce(acc0 + acc1);
    if (lane == 0) Apart[p] = (ti == tj) ? tot : 2.0f * tot;
}

// Kernel 3: finalize. Partial arrays are now 256 entries each.
__global__ __launch_bounds__(256) void k_fin(
    const float* __restrict__ means, const float* __restrict__ vars,
    const float* __restrict__ probs,
    const float* __restrict__ Apart,
    const float* __restrict__ recp, const float* __restrict__ Bp,
    const float* __restrict__ clsp, const float* __restrict__ labp,
    float* __restrict__ out, float gamma)
{
    __shared__ double wsum[8];
    const int t = threadIdx.x;
    const int w = t >> 6;
    const int l = t & 63;

    const double m = (double)M_ROWS;
    const double gam = (double)gamma;
    const double invA = 1.0 / (m * m * sqrt(2.0 * M_PI * 2.0 * gam));

    double av = 0.0;
#pragma unroll
    for (int k = 0; k < 9; k++) {
        int idx = t + 256 * k;
        if (idx < NPAIR) av += (double)Apart[idx];
    }

    double cv = 0.0;
    if (t < 100) {
        int ci = t / 10, cj = t - 10 * (t / 10);
        float vm = vars[ci] + vars[cj];
        float d0 = means[2 * ci] - means[2 * cj];
        float d1 = means[2 * ci + 1] - means[2 * cj + 1];
        float c1 = fmaf(d0, d0, d1 * d1);
        float s = c1 / (2.0f * vm + 4.0f * gamma);
        float c2 = phi_eval(s);
        float c3 = probs[ci] * probs[cj] * __builtin_amdgcn_rsqf(TWO_PI_F * (vm + 2.0f * gamma));
        cv = (double)(c3 * c2);
    }

    double acw = waveReduceD(av * invA + cv);

    const float* arr = (w == 0) ? recp : (w == 1) ? Bp : (w == 2) ? clsp : labp;
    double pv = 0.0;
#pragma unroll
    for (int k = 0; k < 4; k++) pv += (double)arr[l + 64 * k];
    double pw = waveReduceD(pv);

    if (l == 0) { wsum[w] = acw; wsum[4 + w] = pw; }
    __syncthreads();

    if (t == 0) {
        double AC = wsum[0] + wsum[1] + wsum[2] + wsum[3];
        double rec = wsum[4], B = wsum[5], cls = wsum[6], lab = wsum[7];
        double den = (lab == 0.0) ? 1.0 : lab;
        double cw = AC - B;
        double total = rec / (m * 64.0) + 8.0 + log(cw) + 2.0 * (cls / den);
        out[0] = (float)total;
    }
}

extern "C" void kernel_launch(void* const* d_in, const int* in_sizes, int n_in,
                              void* d_out, int out_size, void* d_ws, size_t ws_size,
                              hipStream_t stream) {
    (void)in_sizes; (void)n_in; (void)out_size; (void)ws_size;
    const float* batch = (const float*)d_in[0];
    const float* We1 = (const float*)d_in[1];
    const float* be1 = (const float*)d_in[2];
    const float* We2 = (const float*)d_in[3];
    const float* be2 = (const float*)d_in[4];
    const float* We3 = (const float*)d_in[5];
    const float* be3 = (const float*)d_in[6];
    const float* Wd1 = (const float*)d_in[7];
    const float* bd1 = (const float*)d_in[8];
    const float* Wd2 = (const float*)d_in[9];
    const float* bd2 = (const float*)d_in[10];
    const float* Wd3 = (const float*)d_in[11];
    const float* bd3 = (const float*)d_in[12];
    const float* means = (const float*)d_in[13];
    const float* vars = (const float*)d_in[14];
    const float* probs = (const float*)d_in[15];

    float* ws = (float*)d_ws;
    float2* zbuf = (float2*)ws;          // 4096 float2
    float* Apart = ws + 8192;            // 2080
    float* recp  = ws + 12288;           // 256
    float* Bp    = ws + 12544;           // 256
    float* clsp  = ws + 12800;           // 256
    float* labp  = ws + 13056;           // 256

    const float gamma = (float)pow(4.0 / (3.0 * (double)M_ROWS), 0.2);
    const float inv4g = 1.0f / (4.0f * gamma);

    k_mlp<<<NBLK_MLP, 64, 0, stream>>>(batch, We1, be1, We2, be2, We3, be3,
                                       Wd1, bd1, Wd2, bd2, Wd3, bd3,
                                       means, vars, probs,
                                       zbuf, recp, Bp, clsp, labp, gamma);
    k_pair<<<NPAIR, 64, 0, stream>>>(zbuf, Apart, inv4g);
    k_fin<<<1, 256, 0, stream>>>(means, vars, probs, Apart, recp, Bp, clsp, labp,
                                 (float*)d_out, gamma);
}